// Round 2
// baseline (910.153 us; speedup 1.0000x reference)
//
#include <hip/hip_runtime.h>

#define EB 4          // edges per block
#define NT 384        // threads per block (6 waves)
#define W3STRIDE 36   // padded LDS stride (rows stay 16B-aligned; +4 rotates banks per row)

__global__ __launch_bounds__(NT) void singleconv_fused(
    const float* __restrict__ f,
    const float* __restrict__ basis,
    const float* __restrict__ w1,
    const float* __restrict__ b1,
    const float* __restrict__ g1,
    const float* __restrict__ be1,
    const float* __restrict__ w2,
    const float* __restrict__ b2,
    const float* __restrict__ g2,
    const float* __restrict__ be2,
    const float* __restrict__ w3,
    const float* __restrict__ b3,
    float* __restrict__ out)
{
    __shared__ float sf[EB][17];
    __shared__ float sbas[EB][27];
    __shared__ float sh1[EB][32];
    __shared__ alignas(16) float sh2[EB][32];
    __shared__ float smu[EB], srs[EB];
    __shared__ alignas(16) float sw3[96 * W3STRIDE];
    __shared__ float sr[EB * 96];

    const int t  = threadIdx.x;
    const int e0 = blockIdx.x * EB;

    // ---------------- phase 1: load f, basis ----------------
    if (t < EB * 17) {
        int e = t / 17, i = t - e * 17;
        sf[e][i] = f[(e0 + e) * 17 + i];
    }
    if (t >= 128 && t < 128 + EB * 27) {
        int q = t - 128;
        int e = q / 27, i = q - e * 27;
        sbas[e][i] = basis[(e0 + e) * 27 + i];
    }
    __syncthreads();

    // ---- layer 1: h1 = f @ w1.T + b1 ----
    if (t < EB * 32) {
        int e = t >> 5, j = t & 31;
        float acc = b1[j];
        #pragma unroll
        for (int k = 0; k < 17; k++) acc += sf[e][k] * w1[j * 17 + k];
        sh1[e][j] = acc;
    }
    __syncthreads();
    if (t < EB) {
        float mu = 0.f;
        #pragma unroll
        for (int j = 0; j < 32; j++) mu += sh1[t][j];
        mu *= (1.f / 32.f);
        float var = 0.f;
        #pragma unroll
        for (int j = 0; j < 32; j++) { float d = sh1[t][j] - mu; var += d * d; }
        var *= (1.f / 32.f);
        smu[t] = mu; srs[t] = rsqrtf(var + 1e-5f);
    }
    __syncthreads();
    if (t < EB * 32) {
        int e = t >> 5, j = t & 31;
        float y = (sh1[e][j] - smu[e]) * srs[e] * g1[j] + be1[j];
        sh1[e][j] = fmaxf(y, 0.f);
    }
    __syncthreads();

    // ---- layer 2: h2 = h1 @ w2.T + b2 ----
    if (t < EB * 32) {
        int e = t >> 5, j = t & 31;
        float acc = b2[j];
        #pragma unroll
        for (int k = 0; k < 32; k++) acc += sh1[e][k] * w2[j * 32 + k];
        sh2[e][j] = acc;
    }
    __syncthreads();
    if (t < EB) {
        float mu = 0.f;
        #pragma unroll
        for (int j = 0; j < 32; j++) mu += sh2[t][j];
        mu *= (1.f / 32.f);
        float var = 0.f;
        #pragma unroll
        for (int j = 0; j < 32; j++) { float d = sh2[t][j] - mu; var += d * d; }
        var *= (1.f / 32.f);
        smu[t] = mu; srs[t] = rsqrtf(var + 1e-5f);
    }
    __syncthreads();
    if (t < EB * 32) {
        int e = t >> 5, j = t & 31;
        float y = (sh2[e][j] - smu[e]) * srs[e] * g2[j] + be2[j];
        sh2[e][j] = fmaxf(y, 0.f);
    }
    __syncthreads();

    // ---------------- phase 2: per-co chunks ----------------
    const int re   = t / 96;        // edge for r-compute, 0..3
    const int rcol = t - re * 96;   // 0..95 (= ci*3 + freq)
    const int wrow = t >> 2;        // w3 staging: row within chunk (0..95)
    const int wk   = (t & 3) * 8;   // w3 staging: k offset (0,8,16,24)

    // epilogue mapping (3 outputs/thread), loop-invariant
    int ep_srb[3], ep_sbb[3], ep_off[3], ep_row[3];
    #pragma unroll
    for (int s = 0; s < 3; s++) {
        int idx  = t + s * NT;            // 0..1151
        int e    = idx / 288;
        int rem  = idx - e * 288;
        int dord = rem / 96;
        int c    = rem - dord * 96;
        int ci   = c / 3;
        int di   = c - ci * 3;
        ep_srb[s] = e * 96 + ci * 3;
        ep_sbb[s] = e * 27 + dord * 9 + di * 3;
        ep_row[s] = dord;
        ep_off[s] = (e0 + e) * 9216 + c;  // + (co*3+dord)*96 added per-iter
    }
    const float* sbf = &sbas[0][0];

    for (int co = 0; co < 32; co++) {
        __syncthreads();  // previous epilogue done; sr / sw3 free

        // stage w3 chunk (96 rows x 32 k, fp32, 12 KB) into LDS
        {
            const float4* wsrc = (const float4*)(w3 + co * 3072);
            float4 a = wsrc[t * 2];
            float4 b = wsrc[t * 2 + 1];
            float* wd = &sw3[wrow * W3STRIDE + wk];
            *(float4*)(wd)     = a;
            *(float4*)(wd + 4) = b;
        }
        __syncthreads();

        // r[e][col] = b3 + dot(w3_row, h2[e])
        {
            float acc = b3[co * 96 + rcol];
            const float* wp = &sw3[rcol * W3STRIDE];
            const float* hp = &sh2[re][0];
            #pragma unroll
            for (int k = 0; k < 32; k += 4) {
                float4 w = *(const float4*)(wp + k);
                float4 h = *(const float4*)(hp + k);
                acc += w.x * h.x + w.y * h.y + w.z * h.z + w.w * h.w;
            }
            sr[t] = acc;   // t == re*96 + rcol
        }
        __syncthreads();

        // epilogue: out[e, co*3+do, ci*3+di] = sum_f r[e, ci*3+f] * B[e, do, di, f]
        #pragma unroll
        for (int s = 0; s < 3; s++) {
            const float* rp = &sr[ep_srb[s]];
            const float* bp = sbf + ep_sbb[s];
            float v = rp[0] * bp[0] + rp[1] * bp[1] + rp[2] * bp[2];
            out[ep_off[s] + (co * 3 + ep_row[s]) * 96] = v;
        }
    }
}

extern "C" void kernel_launch(void* const* d_in, const int* in_sizes, int n_in,
                              void* d_out, int out_size, void* d_ws, size_t ws_size,
                              hipStream_t stream) {
    const float* f     = (const float*)d_in[0];
    const float* basis = (const float*)d_in[1];
    const float* w1    = (const float*)d_in[2];
    const float* b1    = (const float*)d_in[3];
    const float* g1    = (const float*)d_in[4];
    const float* be1   = (const float*)d_in[5];
    const float* w2    = (const float*)d_in[6];
    const float* b2    = (const float*)d_in[7];
    const float* g2    = (const float*)d_in[8];
    const float* be2   = (const float*)d_in[9];
    const float* w3    = (const float*)d_in[10];
    const float* b3    = (const float*)d_in[11];
    float* out = (float*)d_out;

    dim3 grid(20000 / EB), block(NT);
    hipLaunchKernelGGL(singleconv_fused, grid, block, 0, stream,
                       f, basis, w1, b1, g1, be1, w2, b2, g2, be2, w3, b3, out);
}